// Round 3
// baseline (373.331 us; speedup 1.0000x reference)
//
#include <hip/hip_runtime.h>
#include <math.h>

#define NDIM 512
#define NROWS 256  // B*S = 2*128

typedef float vfloat4 __attribute__((ext_vector_type(4)));

// ---------------------------------------------------------------------------
// Zero-fill of the std_mat region (256 MB) with coalesced nontemporal 16B
// stores. hipMemsetAsync's fillBufferAligned path measured 4x write
// amplification (1.078 GB written for 269 MB region, ~1.5 TB/s effective) --
// this custom fill should run at ~6 TB/s.
// Grid 2048 x 256: 524288 threads x 32 iters == 16,777,216 x 16B == 256 MB.
// ---------------------------------------------------------------------------
__global__ __launch_bounds__(256) void gs_fill(float* __restrict__ std_base) {
    vfloat4* p = (vfloat4*)std_base;
    size_t idx = (size_t)blockIdx.x * 256 + threadIdx.x;
    const size_t stride = (size_t)2048 * 256;
    const vfloat4 z = {0.f, 0.f, 0.f, 0.f};
    #pragma unroll 4
    for (int it = 0; it < 32; ++it) {
        __builtin_nontemporal_store(z, p + idx);
        idx += stride;
    }
}

// ---------------------------------------------------------------------------
// GEMM + softplus + sample + diagonal scatter.
// 64 blocks x 512 threads; each block handles 4 rows of x (staged in LDS,
// wave-uniform broadcast reads). Thread `c` computes stats columns c (var
// half) and c+512 (mu half) for all 4 rows -> W read once per block
// (2 MB x 64 blocks = 128 MB L2 traffic).
// Runs AFTER gs_fill so the diagonal writes land on the zeroed matrix.
// ---------------------------------------------------------------------------
__global__ __launch_bounds__(512) void gs_gemm(const float* __restrict__ x,
                                               const float* __restrict__ W,
                                               const float* __restrict__ b,
                                               const float* __restrict__ eps,
                                               float* __restrict__ out) {
    __shared__ float xs[4 * NDIM];
    const int r0 = blockIdx.x << 2;
    const int tid = threadIdx.x;

    // 4 rows of x are contiguous in memory: coalesced load into LDS.
    for (int t = tid; t < 4 * NDIM; t += 512)
        xs[t] = x[(size_t)r0 * NDIM + t];
    __syncthreads();

    const int c = tid;  // 0..511
    const float4* wa = (const float4*)(W + (size_t)c * NDIM);          // softplus half
    const float4* wb = (const float4*)(W + (size_t)(c + NDIM) * NDIM); // mu half
    const float4* xs4 = (const float4*)xs;

    float sa[4] = {0.f, 0.f, 0.f, 0.f};
    float sb[4] = {0.f, 0.f, 0.f, 0.f};

    #pragma unroll 4
    for (int k = 0; k < NDIM / 4; ++k) {
        float4 a  = wa[k];
        float4 bv = wb[k];
        #pragma unroll
        for (int rr = 0; rr < 4; ++rr) {
            float4 xv = xs4[rr * (NDIM / 4) + k];  // wave-uniform -> LDS broadcast
            sa[rr] += xv.x * a.x  + xv.y * a.y  + xv.z * a.z  + xv.w * a.w;
            sb[rr] += xv.x * bv.x + xv.y * bv.y + xv.z * bv.z + xv.w * bv.w;
        }
    }

    const float bias_a = b[c];
    const float bias_b = b[c + NDIM];

    float* out_sample = out;
    float* out_mu     = out + (size_t)NROWS * NDIM;
    float* out_std    = out + (size_t)2 * NROWS * NDIM;

    #pragma unroll
    for (int rr = 0; rr < 4; ++rr) {
        const int r = r0 + rr;
        const float s0  = sa[rr] + bias_a;
        const float var = (s0 > 20.f) ? s0 : log1pf(expf(s0));  // softplus
        const float mu  = sb[rr] + bias_b;
        const float smp = mu + sqrtf(var) * eps[(size_t)r * NDIM + c];

        out_sample[(size_t)r * NDIM + c] = smp;
        out_mu[(size_t)r * NDIM + c]     = mu;
        out_std[(size_t)r * NDIM * NDIM + (size_t)c * NDIM + c] = var;
    }
}

extern "C" void kernel_launch(void* const* d_in, const int* in_sizes, int n_in,
                              void* d_out, int out_size, void* d_ws, size_t ws_size,
                              hipStream_t stream) {
    const float* x   = (const float*)d_in[0];
    const float* W   = (const float*)d_in[1];
    const float* b   = (const float*)d_in[2];
    const float* eps = (const float*)d_in[3];
    float* out = (float*)d_out;

    float* std_base = out + (size_t)2 * NROWS * NDIM;  // after sample + mu

    gs_fill<<<2048, 256, 0, stream>>>(std_base);
    gs_gemm<<<64, 512, 0, stream>>>(x, W, b, eps, out);
}